// Round 6
// baseline (163.479 us; speedup 1.0000x reference)
//
#include <hip/hip_runtime.h>
#include <math.h>
#include <stdint.h>

#define N_BINS 50
#define EDGE_N 51
#define HIST_N 52
#define NBLK 2048
#define NTHR 256
#define NREP 16

typedef unsigned int u32;
typedef unsigned short u16;
typedef unsigned char u8;
typedef float f32x4 __attribute__((ext_vector_type(4)));
typedef int i32x4 __attribute__((ext_vector_type(4)));

// ws layout (bytes):
// [0]      float bmin[2048]
// [8192]   float bmax[2048]
// [16384]  int histU[NREP][2*52]   (replicated; zeroed by k_minmax blk0)
// [23040]  int histE[NREP][2*51]
// [32768]  u8 codes[n]             (u | eq<<6 per element)
// [align16] float xc[n]            (compacted column 0)

// jnp.linspace(xmin, xmax, 51) float32 semantics:
//   step = e/50 (f32 div); out = xmin*(1-step) + xmax*step; endpoint = xmax exactly.
__device__ __forceinline__ float edge_at(int e, float xmin, float xmax) {
  if (e >= N_BINS) return xmax;
  float step = __fdiv_rn((float)e, (float)N_BINS);
  float omst = __fsub_rn(1.0f, step);
  return __fadd_rn(__fmul_rn(xmin, omst), __fmul_rn(xmax, step));
}

// bce(c) = ((n_f - c)*b + c*a)/n_f in exact f32 op order (no fma contraction)
__device__ __forceinline__ float bce_f(int c, float n_f, float aC, float bC) {
  float cf = (float)c;  // exact, c < 2^24
  float t = __fadd_rn(__fmul_rn(__fsub_rn(n_f, cf), bC), __fmul_rn(cf, aC));
  return __fdiv_rn(t, n_f);
}

__device__ __forceinline__ void get_ab(float& aC, float& bC) {
  const double epsd = (double)1e-7f;
  aC = (float)(-log1p(-epsd));
  bC = (float)(-log(epsd));
}

// block-wide min/max of bmin/bmax[NBLK] -> s_mm[2] (every block, identical result)
__device__ __forceinline__ void global_minmax(const float* __restrict__ bmin,
                                              const float* __restrict__ bmax,
                                              float* s_red, float* s_mm) {
  const int tid = threadIdx.x;
  float m = INFINITY, M = -INFINITY;
  for (int i = tid; i < NBLK; i += NTHR) { m = fminf(m, bmin[i]); M = fmaxf(M, bmax[i]); }
  for (int off = 32; off; off >>= 1) {
    m = fminf(m, __shfl_down(m, off));
    M = fmaxf(M, __shfl_down(M, off));
  }
  int wid = tid >> 6;
  if ((tid & 63) == 0) { s_red[wid] = m; s_red[4 + wid] = M; }
  __syncthreads();
  if (tid == 0) {
    float mm = s_red[0], MM = s_red[4];
    for (int w = 1; w < NTHR / 64; ++w) { mm = fminf(mm, s_red[w]); MM = fmaxf(MM, s_red[4 + w]); }
    s_mm[0] = mm;
    s_mm[1] = MM;
  }
  __syncthreads();
}

template <int COMPACT>
__global__ void k_minmax(const f32x4* __restrict__ in4, int n,
                         float* __restrict__ bmin, float* __restrict__ bmax,
                         int* __restrict__ histz, float* __restrict__ xc) {
  const int tid = threadIdx.x, bid = blockIdx.x;
  const int gid = bid * NTHR + tid;
  const int stride = NBLK * NTHR;
  const int nt16 = n >> 4;
  const int base = nt16 << 4;
  f32x4* __restrict__ xc4 = (f32x4*)xc;
  if (bid == 0) {  // zero replicated hists (stream-ordered before k_hist)
    for (int i = tid; i < NREP * (2 * HIST_N + 2 * EDGE_N); i += NTHR) histz[i] = 0;
  }
  float vmin = INFINITY, vmax = -INFINITY;
  for (int iv = gid; iv < nt16; iv += stride) {
    float xs[16];
#pragma unroll
    for (int j = 0; j < 16; ++j) {
      f32x4 r = __builtin_nontemporal_load(&in4[16 * iv + j]);
      xs[j] = r.x;
    }
#pragma unroll
    for (int j = 0; j < 16; ++j) { vmin = fminf(vmin, xs[j]); vmax = fmaxf(vmax, xs[j]); }
    if (COMPACT) {
#pragma unroll
      for (int q = 0; q < 4; ++q) {
        f32x4 o = {xs[4 * q], xs[4 * q + 1], xs[4 * q + 2], xs[4 * q + 3]};
        xc4[4 * iv + q] = o;
      }
    }
  }
  if (bid == 0 && tid < (n - base)) {
    f32x4 r = in4[base + tid];
    float x = r.x;
    vmin = fminf(vmin, x);
    vmax = fmaxf(vmax, x);
    if (COMPACT) xc[base + tid] = x;
  }
  for (int off = 32; off; off >>= 1) {
    vmin = fminf(vmin, __shfl_down(vmin, off));
    vmax = fmaxf(vmax, __shfl_down(vmax, off));
  }
  __shared__ float s_red[8];
  int wid = tid >> 6;
  if ((tid & 63) == 0) { s_red[wid] = vmin; s_red[4 + wid] = vmax; }
  __syncthreads();
  if (tid == 0) {
    float m = s_red[0], M = s_red[4];
    for (int w = 1; w < NTHR / 64; ++w) { m = fminf(m, s_red[w]); M = fmaxf(M, s_red[4 + w]); }
    bmin[bid] = m;
    bmax[bid] = M;
  }
}

template <int COMPACT>
__global__ void k_hist(const f32x4* __restrict__ in4, const float* __restrict__ xc,
                       const int* __restrict__ tgt, int n,
                       const float* __restrict__ bmin, const float* __restrict__ bmax,
                       int* __restrict__ histU, int* __restrict__ histE,
                       u8* __restrict__ codes) {
  // per-thread private counters: bank = (tid/2)%32 independent of bin -> conflict-free
  __shared__ u16 ph[HIST_N][NTHR];
  __shared__ float s_edges[EDGE_N];
  __shared__ int shE[2 * EDGE_N];
  __shared__ float s_red[8];
  __shared__ float s_mm[2];
  const int tid = threadIdx.x, bid = blockIdx.x;
  global_minmax(bmin, bmax, s_red, s_mm);
  u32* ph32w = (u32*)&ph[0][0];
  for (int i = tid; i < HIST_N * (NTHR / 2); i += NTHR) ph32w[i] = 0;
  for (int i = tid; i < 2 * EDGE_N; i += NTHR) shE[i] = 0;
  const float xmin = s_mm[0], xmax = s_mm[1];
  if (tid < EDGE_N) s_edges[tid] = edge_at(tid, xmin, xmax);
  __syncthreads();
  const float delta = __fdiv_rn(__fsub_rn(xmax, xmin), (float)N_BINS);
  const float inv_delta = (delta > 0.0f) ? (1.0f / delta) : 0.0f;  // guess only
  const int gid = bid * NTHR + tid;
  const int stride = NBLK * NTHR;
  const int nt16 = n >> 4;
  const int base = nt16 << 4;
  const f32x4* __restrict__ xc4 = (const f32x4*)xc;
  const i32x4* __restrict__ tgt4 = (const i32x4*)tgt;
  i32x4* __restrict__ codes16 = (i32x4*)codes;
  for (int iv = gid; iv < nt16; iv += stride) {
    float xs[16];
    int ts[16];
#pragma unroll
    for (int q = 0; q < 4; ++q) {
      f32x4 v;
      if (COMPACT) v = xc4[4 * iv + q];
      else {
        v.x = in4[16 * iv + 4 * q + 0].x; v.y = in4[16 * iv + 4 * q + 1].x;
        v.z = in4[16 * iv + 4 * q + 2].x; v.w = in4[16 * iv + 4 * q + 3].x;
      }
      i32x4 t = __builtin_nontemporal_load(&tgt4[4 * iv + q]);
      xs[4 * q] = v.x; xs[4 * q + 1] = v.y; xs[4 * q + 2] = v.z; xs[4 * q + 3] = v.w;
      ts[4 * q] = t.x; ts[4 * q + 1] = t.y; ts[4 * q + 2] = t.z; ts[4 * q + 3] = t.w;
    }
    u32 cw[4] = {0, 0, 0, 0};
#pragma unroll
    for (int k = 0; k < 16; ++k) {
      float x = xs[k];
      int cls = (ts[k] == 1) ? 0 : 1;
      int g = (int)((x - xmin) * inv_delta);
      g = max(0, min(g, EDGE_N));
      while (g < EDGE_N && s_edges[g] < x) ++g;   // exact: u = #edges < x
      while (g > 0 && s_edges[g - 1] >= x) --g;
      int eq = (g < EDGE_N && s_edges[g] == x) ? 1 : 0;
      ph[g][tid] = (u16)(ph[g][tid] + (1u << (cls * 8)));
      if (eq) atomicAdd(&shE[cls * EDGE_N + g], 1);
      cw[k >> 2] |= (u32)(g | (eq << 6)) << (8 * (k & 3));
    }
    if (COMPACT) {
      i32x4 cv = {(int)cw[0], (int)cw[1], (int)cw[2], (int)cw[3]};
      codes16[iv] = cv;
    }
  }
  if (bid == 0 && tid < (n - base)) {
    int i = base + tid;
    float x = COMPACT ? xc[i] : in4[i].x;
    int cls = (tgt[i] == 1) ? 0 : 1;
    int g = (int)((x - xmin) * inv_delta);
    g = max(0, min(g, EDGE_N));
    while (g < EDGE_N && s_edges[g] < x) ++g;
    while (g > 0 && s_edges[g - 1] >= x) --g;
    int eq = (g < EDGE_N && s_edges[g] == x) ? 1 : 0;
    ph[g][tid] = (u16)(ph[g][tid] + (1u << (cls * 8)));
    if (eq) atomicAdd(&shE[cls * EDGE_N + g], 1);
    if (COMPACT) codes[i] = (u8)(g | (eq << 6));
  }
  __syncthreads();
  int* hU = histU + (bid & (NREP - 1)) * (2 * HIST_N);
  int* hE = histE + (bid & (NREP - 1)) * (2 * EDGE_N);
  if (tid < HIST_N) {  // lanes 0..51 of wave 0; diagonal stagger -> <=2 lanes/bank
    const u32* ph32r = (const u32*)&ph[0][0];
    u32 c0 = 0, c1 = 0;
    for (int k2 = 0; k2 < NTHR / 2; ++k2) {
      int idx = (k2 + tid) & (NTHR / 2 - 1);
      u32 w = ph32r[tid * (NTHR / 2) + idx];
      c0 += (w & 0xFFu) + ((w >> 16) & 0xFFu);
      c1 += ((w >> 8) & 0xFFu) + ((w >> 24) & 0xFFu);
    }
    if (c0) atomicAdd(&hU[tid], (int)c0);
    if (c1) atomicAdd(&hU[HIST_N + tid], (int)c1);
  }
  for (int kk = tid; kk < 2 * EDGE_N; kk += NTHR) {
    int v = shE[kk];
    if (v) atomicAdd(&hE[kk], v);
  }
}

// decide (redundant per block, bit-identical) + predict, fused
template <int COMPACT>
__global__ void k_decide_pred(const f32x4* __restrict__ in4, const u8* __restrict__ codes,
                              int n, const float* __restrict__ bmin,
                              const float* __restrict__ bmax,
                              const int* __restrict__ histU, const int* __restrict__ histE,
                              int* __restrict__ out) {
  __shared__ float s_red[8];
  __shared__ float s_mm[2];
  __shared__ int s_ns_le[EDGE_N], s_ns_lt[EDGE_N], s_nb_le[EDGE_N], s_nb_lt[EDGE_N];
  __shared__ int s_h0[N_BINS], s_h1[N_BINS];
  __shared__ unsigned char s_g0[N_BINS], s_g1[N_BINS];
  __shared__ unsigned char s_mask[EDGE_N];
  __shared__ float s_rv[NTHR];
  __shared__ int s_ri[NTHR];
  __shared__ int s_cut[3];  // case, i, j
  const int tid = threadIdx.x, bid = blockIdx.x;

  global_minmax(bmin, bmax, s_red, s_mm);

  // ---- wave-parallel prefix sums over summed replicas: wave0=sig, wave1=bkg ----
  if (tid < 128) {
    const int lane = tid & 63;
    const int w = tid >> 6;  // 0: sig, 1: bkg
    int v = 0;
    if (lane < EDGE_N) {
      for (int r = 0; r < NREP; ++r) v += histU[r * (2 * HIST_N) + w * HIST_N + lane];
    }
#pragma unroll
    for (int d = 1; d < 64; d <<= 1) {
      int t = __shfl_up(v, d);
      if (lane >= d) v += t;
    }
    if (lane < EDGE_N) {
      int e = 0;
      for (int r = 0; r < NREP; ++r) e += histE[r * (2 * EDGE_N) + w * EDGE_N + lane];
      if (w == 0) { s_ns_le[lane] = v; s_ns_lt[lane] = v - e; }
      else        { s_nb_le[lane] = v; s_nb_lt[lane] = v - e; }
    }
  }
  if (tid < EDGE_N) s_mask[tid] = 0;
  __syncthreads();
  if (tid < N_BINS) {
    int h0 = s_nb_le[tid + 1] - s_nb_lt[tid];
    int h1 = s_ns_le[tid + 1] - s_ns_lt[tid];
    s_h0[tid] = h0;
    s_h1[tid] = h1;
    s_g0[tid] = h0 > h1;
    s_g1[tid] = h1 > h0;
  }
  __syncthreads();
  if (tid < 64) {  // wave 0: cand for k=0..48 -> mask[k+1]; cnt via ballot
    bool cand = false;
    if (tid + 1 < N_BINS) {
      bool c0 = (s_g0[tid] != s_g0[tid + 1]) && (s_h0[tid] > 0);
      bool c1 = (s_g1[tid] != s_g1[tid + 1]) && (s_h1[tid] > 0);
      cand = c0 || c1;
      if (cand) s_mask[tid + 1] = 1;
    }
    unsigned long long bal = __ballot(cand);
    if (tid == 0 && __popcll(bal) == 1) s_mask[N_BINS] = 1;
  }
  __syncthreads();
  const int Ns = s_ns_le[EDGE_N - 1];
  const int Nb = n - Ns;
  float aC, bC;
  get_ab(aC, bC);
  const float n_f = (float)n;
  float best = INFINITY;
  int bestIdx = 0x7fffffff;
  for (int p = tid; p < EDGE_N * EDGE_N; p += NTHR) {
    int i = p / EDGE_N, j = p - i * EDGE_N;
    float v = INFINITY;
    if (s_mask[i] && s_mask[j] && i < j) {
      int c0 = s_ns_le[i] + (Nb - s_nb_le[i]);
      int c1 = Ns - s_ns_lt[i] + s_nb_lt[i];
      int c2 = s_ns_le[j] - s_ns_lt[i] + Nb - (s_nb_le[j] - s_nb_lt[i]);
      int c3 = s_ns_le[i] + Ns - s_ns_lt[j] + s_nb_le[j] - s_nb_lt[i];
      float L0 = bce_f(c0, n_f, aC, bC);
      float L1 = bce_f(c1, n_f, aC, bC);
      float L2 = bce_f(c2, n_f, aC, bC);
      float L3 = bce_f(c3, n_f, aC, bC);
      v = L0;
      if (L1 < v) v = L1;
      if (L2 < v) v = L2;
      if (L3 < v) v = L3;
    }
    if (v < best || (v == best && p < bestIdx)) { best = v; bestIdx = p; }
  }
  s_rv[tid] = best;
  s_ri[tid] = bestIdx;
  __syncthreads();
  for (int s = NTHR / 2; s > 0; s >>= 1) {
    if (tid < s) {
      float ov = s_rv[tid + s];
      int oi = s_ri[tid + s];
      if (ov < s_rv[tid] || (ov == s_rv[tid] && oi < s_ri[tid])) {
        s_rv[tid] = ov;
        s_ri[tid] = oi;
      }
    }
    __syncthreads();
  }
  if (tid == 0) {
    int p = s_ri[0];
    int i = p / EDGE_N, j = p - i * EDGE_N;
    int c0 = s_ns_le[i] + (Nb - s_nb_le[i]);
    int c1 = Ns - s_ns_lt[i] + s_nb_lt[i];
    int c2 = s_ns_le[j] - s_ns_lt[i] + Nb - (s_nb_le[j] - s_nb_lt[i]);
    int c3 = s_ns_le[i] + Ns - s_ns_lt[j] + s_nb_le[j] - s_nb_lt[i];
    float L0 = bce_f(c0, n_f, aC, bC);
    float L1 = bce_f(c1, n_f, aC, bC);
    float L2 = bce_f(c2, n_f, aC, bC);
    float L3 = bce_f(c3, n_f, aC, bC);
    int cs = 0;
    float m = L0;
    if (L1 < m) { m = L1; cs = 1; }
    if (L2 < m) { m = L2; cs = 2; }
    if (L3 < m) { m = L3; cs = 3; }
    s_cut[0] = cs;
    s_cut[1] = i;
    s_cut[2] = j;
  }
  __syncthreads();

  // ---- predict ----
  const int cs = s_cut[0], ci = s_cut[1], cj = s_cut[2];
  const int gid = bid * NTHR + tid;
  const int stride = NBLK * NTHR;
  if (COMPACT) {
    const i32x4* __restrict__ c16 = (const i32x4*)codes;
    i32x4* __restrict__ out4 = (i32x4*)out;
    const int ncv = n >> 4;
    for (int iv = gid; iv < ncv; iv += stride) {
      i32x4 c = c16[iv];
      u32 wv[4] = {(u32)c.x, (u32)c.y, (u32)c.z, (u32)c.w};
#pragma unroll
      for (int q = 0; q < 4; ++q) {
        u32 w = wv[q];
        int r[4];
#pragma unroll
        for (int b = 0; b < 4; ++b) {
          u32 by = (w >> (8 * b)) & 0xFFu;
          int u = (int)(by & 63u);
          int v = u + (int)(by >> 6);
          bool p0 = (u <= ci), p1 = (ci < v);
          bool p = (cs == 0) ? p0 : (cs == 1) ? p1 : (cs == 2) ? (p1 && (u <= cj)) : (p0 || (cj < v));
          r[b] = p ? 1 : 0;
        }
        i32x4 ov = {r[0], r[1], r[2], r[3]};
        __builtin_nontemporal_store(ov, &out4[iv * 4 + q]);
      }
    }
    const int cbase = ncv << 4;
    if (bid == 0 && tid < (n - cbase)) {
      int i = cbase + tid;
      u32 by = codes[i];
      int u = (int)(by & 63u);
      int v = u + (int)(by >> 6);
      bool p0 = (u <= ci), p1 = (ci < v);
      bool p = (cs == 0) ? p0 : (cs == 1) ? p1 : (cs == 2) ? (p1 && (u <= cj)) : (p0 || (cj < v));
      out[i] = p ? 1 : 0;
    }
  } else {
    const float xmin = s_mm[0], xmax = s_mm[1];
    const float lower = edge_at(ci, xmin, xmax);
    const float upper = edge_at(cj, xmin, xmax);
    i32x4* __restrict__ out4 = (i32x4*)out;
    const int nv = n >> 2;
    for (int iv = gid; iv < nv; iv += stride) {
      float xs[4] = {in4[4 * iv + 0].x, in4[4 * iv + 1].x, in4[4 * iv + 2].x, in4[4 * iv + 3].x};
      int r[4];
#pragma unroll
      for (int k = 0; k < 4; ++k) {
        float x = xs[k];
        bool p;
        if (cs == 0) p = (x <= lower);
        else if (cs == 1) p = (x >= lower);
        else if (cs == 2) p = (x >= lower) && (x <= upper);
        else p = (x <= lower) || (x >= upper);
        r[k] = p ? 1 : 0;
      }
      i32x4 ov = {r[0], r[1], r[2], r[3]};
      __builtin_nontemporal_store(ov, &out4[iv]);
    }
    const int fbase = nv << 2;
    if (bid == 0 && tid < (n - fbase)) {
      int i = fbase + tid;
      float x = in4[i].x;
      bool p;
      if (cs == 0) p = (x <= lower);
      else if (cs == 1) p = (x >= lower);
      else if (cs == 2) p = (x >= lower) && (x <= upper);
      else p = (x <= lower) || (x >= upper);
      out[i] = p ? 1 : 0;
    }
  }
}

extern "C" void kernel_launch(void* const* d_in, const int* in_sizes, int n_in,
                              void* d_out, int out_size, void* d_ws, size_t ws_size,
                              hipStream_t stream) {
  const f32x4* in4 = (const f32x4*)d_in[0];
  const int* tgt = (const int*)d_in[1];
  int n = in_sizes[1];
  int* out = (int*)d_out;
  char* ws = (char*)d_ws;
  float* bmin = (float*)ws;
  float* bmax = (float*)(ws + 8192);
  int* histU = (int*)(ws + 16384);
  int* histE = (int*)(ws + 16384 + NREP * 2 * HIST_N * 4);
  u8* codes = (u8*)(ws + 32768);
  size_t xcOff = ((size_t)32768 + (size_t)n + 15) & ~(size_t)15;
  float* xc = (float*)(ws + xcOff);
  const bool compact = ws_size >= xcOff + (size_t)n * 4u;

  if (compact) {
    k_minmax<1><<<NBLK, NTHR, 0, stream>>>(in4, n, bmin, bmax, histU, xc);
    k_hist<1><<<NBLK, NTHR, 0, stream>>>(in4, xc, tgt, n, bmin, bmax, histU, histE, codes);
    k_decide_pred<1><<<NBLK, NTHR, 0, stream>>>(in4, codes, n, bmin, bmax, histU, histE, out);
  } else {
    k_minmax<0><<<NBLK, NTHR, 0, stream>>>(in4, n, bmin, bmax, histU, nullptr);
    k_hist<0><<<NBLK, NTHR, 0, stream>>>(in4, nullptr, tgt, n, bmin, bmax, histU, histE, nullptr);
    k_decide_pred<0><<<NBLK, NTHR, 0, stream>>>(in4, nullptr, n, bmin, bmax, histU, histE, out);
  }
}

// Round 7
// 105.128 us; speedup vs baseline: 1.5551x; 1.5551x over previous
//
#include <hip/hip_runtime.h>
#include <math.h>
#include <stdint.h>

#define N_BINS 50
#define EDGE_N 51
#define HIST_N 52
#define NBLK 2048
#define NTHR 256

typedef unsigned int u32;
typedef unsigned short u16;
typedef unsigned char u8;
typedef float f32x4 __attribute__((ext_vector_type(4)));

// ws layout (bytes):
// [0]      float bmin[2048]
// [8192]   float bmax[2048]
// [16448]  int histU[2*52]           (U_sig, U_bkg; zeroed by k_minmax blk0)
// [+416]   int histE[2*51]
// [32768]  u8 codes[n]               (u | eq<<6 per element)
// [align16] float xc[n]              (compacted column 0)

// force the full 16B load to survive (compiler narrows float4 loads to
// scalar dword when only .x is used -> latency-bound 1.1 TB/s, R1 evidence)
#define KEEP16(v) asm volatile("" :: "v"(v))

// jnp.linspace(xmin, xmax, 51) float32 semantics:
//   step = e/50 (f32 div); out = xmin*(1-step) + xmax*step; endpoint = xmax exactly.
__device__ __forceinline__ float edge_at(int e, float xmin, float xmax) {
  if (e >= N_BINS) return xmax;
  float step = __fdiv_rn((float)e, (float)N_BINS);
  float omst = __fsub_rn(1.0f, step);
  return __fadd_rn(__fmul_rn(xmin, omst), __fmul_rn(xmax, step));
}

// bce(c) = ((n_f - c)*b + c*a)/n_f in exact f32 op order (no fma contraction)
__device__ __forceinline__ float bce_f(int c, float n_f, float aC, float bC) {
  float cf = (float)c;  // exact, c < 2^24
  float t = __fadd_rn(__fmul_rn(__fsub_rn(n_f, cf), bC), __fmul_rn(cf, aC));
  return __fdiv_rn(t, n_f);
}

__device__ __forceinline__ void get_ab(float& aC, float& bC) {
  const double epsd = (double)1e-7f;
  aC = (float)(-log1p(-epsd));
  bC = (float)(-log(epsd));
}

// block-wide min/max of bmin/bmax[NBLK] -> s_mm[2] (every block, identical result)
__device__ __forceinline__ void global_minmax(const float* __restrict__ bmin,
                                              const float* __restrict__ bmax,
                                              float* s_red, float* s_mm) {
  const int tid = threadIdx.x;
  float m = INFINITY, M = -INFINITY;
  for (int i = tid; i < NBLK; i += NTHR) { m = fminf(m, bmin[i]); M = fmaxf(M, bmax[i]); }
  for (int off = 32; off; off >>= 1) {
    m = fminf(m, __shfl_down(m, off));
    M = fmaxf(M, __shfl_down(M, off));
  }
  int wid = tid >> 6;
  if ((tid & 63) == 0) { s_red[wid] = m; s_red[4 + wid] = M; }
  __syncthreads();
  if (tid == 0) {
    float mm = s_red[0], MM = s_red[4];
    for (int w = 1; w < NTHR / 64; ++w) { mm = fminf(mm, s_red[w]); MM = fmaxf(MM, s_red[4 + w]); }
    s_mm[0] = mm;
    s_mm[1] = MM;
  }
  __syncthreads();
}

template <int COMPACT>
__global__ void k_minmax(const f32x4* __restrict__ in4, int n,
                         float* __restrict__ bmin, float* __restrict__ bmax,
                         int* __restrict__ histU, int* __restrict__ histE,
                         float* __restrict__ xc) {
  const int tid = threadIdx.x, bid = blockIdx.x;
  const int gid = bid * NTHR + tid;
  const int stride = NBLK * NTHR;
  const int nv = n >> 2;
  const int base = nv << 2;
  f32x4* __restrict__ xc4 = (f32x4*)xc;
  if (bid == 0) {  // zero global hists (stream-ordered before k_hist)
    for (int i = tid; i < 2 * HIST_N; i += NTHR) histU[i] = 0;
    for (int i = tid; i < 2 * EDGE_N; i += NTHR) histE[i] = 0;
  }
  float vmin = INFINITY, vmax = -INFINITY;
  for (int iv = gid; iv < nv; iv += stride) {
    f32x4 a = in4[4 * iv + 0];
    f32x4 b = in4[4 * iv + 1];
    f32x4 c = in4[4 * iv + 2];
    f32x4 d = in4[4 * iv + 3];
    KEEP16(a); KEEP16(b); KEEP16(c); KEEP16(d);
    vmin = fminf(fminf(vmin, fminf(a.x, b.x)), fminf(c.x, d.x));
    vmax = fmaxf(fmaxf(vmax, fmaxf(a.x, b.x)), fmaxf(c.x, d.x));
    if (COMPACT) {
      f32x4 o = {a.x, b.x, c.x, d.x};
      xc4[iv] = o;
    }
  }
  if (bid == 0 && tid < (n - base)) {
    f32x4 r = in4[base + tid];
    float x = r.x;
    vmin = fminf(vmin, x);
    vmax = fmaxf(vmax, x);
    if (COMPACT) xc[base + tid] = x;
  }
  for (int off = 32; off; off >>= 1) {
    vmin = fminf(vmin, __shfl_down(vmin, off));
    vmax = fmaxf(vmax, __shfl_down(vmax, off));
  }
  __shared__ float s_red[8];
  int wid = tid >> 6;
  if ((tid & 63) == 0) { s_red[wid] = vmin; s_red[4 + wid] = vmax; }
  __syncthreads();
  if (tid == 0) {
    float m = s_red[0], M = s_red[4];
    for (int w = 1; w < NTHR / 64; ++w) { m = fminf(m, s_red[w]); M = fmaxf(M, s_red[4 + w]); }
    bmin[bid] = m;
    bmax[bid] = M;
  }
}

template <int COMPACT>
__global__ void k_hist(const f32x4* __restrict__ in4, const float* __restrict__ xc,
                       const int* __restrict__ tgt, int n,
                       const float* __restrict__ bmin, const float* __restrict__ bmax,
                       int* __restrict__ histU, int* __restrict__ histE,
                       u8* __restrict__ codes) {
  // per-thread private counters: bank = (tid/2)%32 independent of bin -> conflict-free
  __shared__ u16 ph[HIST_N][NTHR];
  __shared__ float s_edges[EDGE_N];
  __shared__ int shE[2 * EDGE_N];
  __shared__ float s_red[8];
  __shared__ float s_mm[2];
  const int tid = threadIdx.x, bid = blockIdx.x;
  global_minmax(bmin, bmax, s_red, s_mm);
  u32* ph32w = (u32*)&ph[0][0];
  for (int i = tid; i < HIST_N * (NTHR / 2); i += NTHR) ph32w[i] = 0;
  for (int i = tid; i < 2 * EDGE_N; i += NTHR) shE[i] = 0;
  const float xmin = s_mm[0], xmax = s_mm[1];
  if (tid < EDGE_N) s_edges[tid] = edge_at(tid, xmin, xmax);
  __syncthreads();
  const float delta = __fdiv_rn(__fsub_rn(xmax, xmin), (float)N_BINS);
  const float inv_delta = (delta > 0.0f) ? (1.0f / delta) : 0.0f;  // guess only
  const int gid = bid * NTHR + tid;
  const int stride = NBLK * NTHR;
  const int nv = n >> 2;
  const int base = nv << 2;
  const f32x4* __restrict__ xc4 = (const f32x4*)xc;
  const int4* __restrict__ tgt4 = (const int4*)tgt;
  uchar4* __restrict__ codes4 = (uchar4*)codes;
  for (int iv = gid; iv < nv; iv += stride) {
    float xs[4];
    if (COMPACT) {
      f32x4 v = xc4[iv];
      xs[0] = v.x; xs[1] = v.y; xs[2] = v.z; xs[3] = v.w;
    } else {
      f32x4 a = in4[4 * iv + 0], b = in4[4 * iv + 1], c = in4[4 * iv + 2], d = in4[4 * iv + 3];
      KEEP16(a); KEEP16(b); KEEP16(c); KEEP16(d);
      xs[0] = a.x; xs[1] = b.x; xs[2] = c.x; xs[3] = d.x;
    }
    int4 tv = tgt4[iv];
    int ts[4] = {tv.x, tv.y, tv.z, tv.w};
    u8 cd[4];
#pragma unroll
    for (int k = 0; k < 4; ++k) {
      float x = xs[k];
      int cls = (ts[k] == 1) ? 0 : 1;
      int g = (int)((x - xmin) * inv_delta);
      g = max(0, min(g, EDGE_N));
      while (g < EDGE_N && s_edges[g] < x) ++g;   // exact: u = #edges < x
      while (g > 0 && s_edges[g - 1] >= x) --g;
      int eq = (g < EDGE_N && s_edges[g] == x) ? 1 : 0;
      ph[g][tid] = (u16)(ph[g][tid] + (1u << (cls * 8)));
      if (eq) atomicAdd(&shE[cls * EDGE_N + g], 1);
      cd[k] = (u8)(g | (eq << 6));
    }
    if (COMPACT) codes4[iv] = make_uchar4(cd[0], cd[1], cd[2], cd[3]);
  }
  if (bid == 0 && tid < (n - base)) {
    int i = base + tid;
    float x = COMPACT ? xc[i] : in4[i].x;
    int cls = (tgt[i] == 1) ? 0 : 1;
    int g = (int)((x - xmin) * inv_delta);
    g = max(0, min(g, EDGE_N));
    while (g < EDGE_N && s_edges[g] < x) ++g;
    while (g > 0 && s_edges[g - 1] >= x) --g;
    int eq = (g < EDGE_N && s_edges[g] == x) ? 1 : 0;
    ph[g][tid] = (u16)(ph[g][tid] + (1u << (cls * 8)));
    if (eq) atomicAdd(&shE[cls * EDGE_N + g], 1);
    if (COMPACT) codes[i] = (u8)(g | (eq << 6));
  }
  __syncthreads();
  if (tid < HIST_N) {  // lanes 0..51 of wave 0; diagonal stagger -> <=2 lanes/bank
    const u32* ph32r = (const u32*)&ph[0][0];
    u32 c0 = 0, c1 = 0;
    for (int k2 = 0; k2 < NTHR / 2; ++k2) {
      int idx = (k2 + tid) & (NTHR / 2 - 1);
      u32 w = ph32r[tid * (NTHR / 2) + idx];
      c0 += (w & 0xFFu) + ((w >> 16) & 0xFFu);
      c1 += ((w >> 8) & 0xFFu) + ((w >> 24) & 0xFFu);
    }
    if (c0) atomicAdd(&histU[tid], (int)c0);
    if (c1) atomicAdd(&histU[HIST_N + tid], (int)c1);
  }
  for (int kk = tid; kk < 2 * EDGE_N; kk += NTHR) {
    int v = shE[kk];
    if (v) atomicAdd(&histE[kk], v);
  }
}

// decide (redundant per block, bit-identical) + predict, fused
template <int COMPACT>
__global__ void k_decide_pred(const f32x4* __restrict__ in4, const u8* __restrict__ codes,
                              int n, const float* __restrict__ bmin,
                              const float* __restrict__ bmax,
                              const int* __restrict__ histU, const int* __restrict__ histE,
                              int* __restrict__ out) {
  __shared__ float s_red[8];
  __shared__ float s_mm[2];
  __shared__ int s_ns_le[EDGE_N], s_ns_lt[EDGE_N], s_nb_le[EDGE_N], s_nb_lt[EDGE_N];
  __shared__ int s_h0[N_BINS], s_h1[N_BINS];
  __shared__ unsigned char s_g0[N_BINS], s_g1[N_BINS];
  __shared__ unsigned char s_mask[EDGE_N];
  __shared__ float s_rv[NTHR];
  __shared__ int s_ri[NTHR];
  __shared__ int s_cut[3];  // case, i, j
  const int tid = threadIdx.x, bid = blockIdx.x;

  global_minmax(bmin, bmax, s_red, s_mm);

  // ---- wave-parallel prefix sums: wave0=sig, wave1=bkg ----
  if (tid < 128) {
    const int lane = tid & 63;
    const int w = tid >> 6;  // 0: sig, 1: bkg
    int v = (lane < EDGE_N) ? histU[w * HIST_N + lane] : 0;
#pragma unroll
    for (int d = 1; d < 64; d <<= 1) {
      int t = __shfl_up(v, d);
      if (lane >= d) v += t;
    }
    if (lane < EDGE_N) {
      int e = histE[w * EDGE_N + lane];
      if (w == 0) { s_ns_le[lane] = v; s_ns_lt[lane] = v - e; }
      else        { s_nb_le[lane] = v; s_nb_lt[lane] = v - e; }
    }
  }
  if (tid < EDGE_N) s_mask[tid] = 0;
  __syncthreads();
  if (tid < N_BINS) {
    int h0 = s_nb_le[tid + 1] - s_nb_lt[tid];
    int h1 = s_ns_le[tid + 1] - s_ns_lt[tid];
    s_h0[tid] = h0;
    s_h1[tid] = h1;
    s_g0[tid] = h0 > h1;
    s_g1[tid] = h1 > h0;
  }
  __syncthreads();
  if (tid < 64) {  // wave 0: cand for k=0..48 -> mask[k+1]; cnt via ballot
    bool cand = false;
    if (tid + 1 < N_BINS) {
      bool c0 = (s_g0[tid] != s_g0[tid + 1]) && (s_h0[tid] > 0);
      bool c1 = (s_g1[tid] != s_g1[tid + 1]) && (s_h1[tid] > 0);
      cand = c0 || c1;
      if (cand) s_mask[tid + 1] = 1;
    }
    unsigned long long bal = __ballot(cand);
    if (tid == 0 && __popcll(bal) == 1) s_mask[N_BINS] = 1;
  }
  __syncthreads();
  const int Ns = s_ns_le[EDGE_N - 1];
  const int Nb = n - Ns;
  float aC, bC;
  get_ab(aC, bC);
  const float n_f = (float)n;
  float best = INFINITY;
  int bestIdx = 0x7fffffff;
  for (int p = tid; p < EDGE_N * EDGE_N; p += NTHR) {
    int i = p / EDGE_N, j = p - i * EDGE_N;
    float v = INFINITY;
    if (s_mask[i] && s_mask[j] && i < j) {
      int c0 = s_ns_le[i] + (Nb - s_nb_le[i]);
      int c1 = Ns - s_ns_lt[i] + s_nb_lt[i];
      int c2 = s_ns_le[j] - s_ns_lt[i] + Nb - (s_nb_le[j] - s_nb_lt[i]);
      int c3 = s_ns_le[i] + Ns - s_ns_lt[j] + s_nb_le[j] - s_nb_lt[i];
      float L0 = bce_f(c0, n_f, aC, bC);
      float L1 = bce_f(c1, n_f, aC, bC);
      float L2 = bce_f(c2, n_f, aC, bC);
      float L3 = bce_f(c3, n_f, aC, bC);
      v = L0;
      if (L1 < v) v = L1;
      if (L2 < v) v = L2;
      if (L3 < v) v = L3;
    }
    if (v < best || (v == best && p < bestIdx)) { best = v; bestIdx = p; }
  }
  s_rv[tid] = best;
  s_ri[tid] = bestIdx;
  __syncthreads();
  for (int s = NTHR / 2; s > 0; s >>= 1) {
    if (tid < s) {
      float ov = s_rv[tid + s];
      int oi = s_ri[tid + s];
      if (ov < s_rv[tid] || (ov == s_rv[tid] && oi < s_ri[tid])) {
        s_rv[tid] = ov;
        s_ri[tid] = oi;
      }
    }
    __syncthreads();
  }
  if (tid == 0) {
    int p = s_ri[0];
    int i = p / EDGE_N, j = p - i * EDGE_N;
    int c0 = s_ns_le[i] + (Nb - s_nb_le[i]);
    int c1 = Ns - s_ns_lt[i] + s_nb_lt[i];
    int c2 = s_ns_le[j] - s_ns_lt[i] + Nb - (s_nb_le[j] - s_nb_lt[i]);
    int c3 = s_ns_le[i] + Ns - s_ns_lt[j] + s_nb_le[j] - s_nb_lt[i];
    float L0 = bce_f(c0, n_f, aC, bC);
    float L1 = bce_f(c1, n_f, aC, bC);
    float L2 = bce_f(c2, n_f, aC, bC);
    float L3 = bce_f(c3, n_f, aC, bC);
    int cs = 0;
    float m = L0;
    if (L1 < m) { m = L1; cs = 1; }
    if (L2 < m) { m = L2; cs = 2; }
    if (L3 < m) { m = L3; cs = 3; }
    s_cut[0] = cs;
    s_cut[1] = i;
    s_cut[2] = j;
  }
  __syncthreads();

  // ---- predict ----
  const int cs = s_cut[0], ci = s_cut[1], cj = s_cut[2];
  const int gid = bid * NTHR + tid;
  const int stride = NBLK * NTHR;
  if (COMPACT) {
    const int4* __restrict__ c16 = (const int4*)codes;
    int4* __restrict__ out4 = (int4*)out;
    const int ncv = n >> 4;
    for (int iv = gid; iv < ncv; iv += stride) {
      int4 c = c16[iv];
      u32 wv[4] = {(u32)c.x, (u32)c.y, (u32)c.z, (u32)c.w};
#pragma unroll
      for (int q = 0; q < 4; ++q) {
        u32 w = wv[q];
        int r[4];
#pragma unroll
        for (int b = 0; b < 4; ++b) {
          u32 by = (w >> (8 * b)) & 0xFFu;
          int u = (int)(by & 63u);
          int v = u + (int)(by >> 6);
          bool p0 = (u <= ci), p1 = (ci < v);
          bool p = (cs == 0) ? p0 : (cs == 1) ? p1 : (cs == 2) ? (p1 && (u <= cj)) : (p0 || (cj < v));
          r[b] = p ? 1 : 0;
        }
        out4[iv * 4 + q] = make_int4(r[0], r[1], r[2], r[3]);
      }
    }
    const int cbase = ncv << 4;
    if (bid == 0 && tid < (n - cbase)) {
      int i = cbase + tid;
      u32 by = codes[i];
      int u = (int)(by & 63u);
      int v = u + (int)(by >> 6);
      bool p0 = (u <= ci), p1 = (ci < v);
      bool p = (cs == 0) ? p0 : (cs == 1) ? p1 : (cs == 2) ? (p1 && (u <= cj)) : (p0 || (cj < v));
      out[i] = p ? 1 : 0;
    }
  } else {
    const float xmin = s_mm[0], xmax = s_mm[1];
    const float lower = edge_at(ci, xmin, xmax);
    const float upper = edge_at(cj, xmin, xmax);
    int4* __restrict__ out4 = (int4*)out;
    const int nv = n >> 2;
    for (int iv = gid; iv < nv; iv += stride) {
      f32x4 a = in4[4 * iv + 0], b = in4[4 * iv + 1], c = in4[4 * iv + 2], d = in4[4 * iv + 3];
      KEEP16(a); KEEP16(b); KEEP16(c); KEEP16(d);
      float xs[4] = {a.x, b.x, c.x, d.x};
      int r[4];
#pragma unroll
      for (int k = 0; k < 4; ++k) {
        float x = xs[k];
        bool p;
        if (cs == 0) p = (x <= lower);
        else if (cs == 1) p = (x >= lower);
        else if (cs == 2) p = (x >= lower) && (x <= upper);
        else p = (x <= lower) || (x >= upper);
        r[k] = p ? 1 : 0;
      }
      out4[iv] = make_int4(r[0], r[1], r[2], r[3]);
    }
    const int fbase = nv << 2;
    if (bid == 0 && tid < (n - fbase)) {
      int i = fbase + tid;
      float x = in4[i].x;
      bool p;
      if (cs == 0) p = (x <= lower);
      else if (cs == 1) p = (x >= lower);
      else if (cs == 2) p = (x >= lower) && (x <= upper);
      else p = (x <= lower) || (x >= upper);
      out[i] = p ? 1 : 0;
    }
  }
}

extern "C" void kernel_launch(void* const* d_in, const int* in_sizes, int n_in,
                              void* d_out, int out_size, void* d_ws, size_t ws_size,
                              hipStream_t stream) {
  const f32x4* in4 = (const f32x4*)d_in[0];
  const int* tgt = (const int*)d_in[1];
  int n = in_sizes[1];
  int* out = (int*)d_out;
  char* ws = (char*)d_ws;
  float* bmin = (float*)ws;
  float* bmax = (float*)(ws + 8192);
  int* histU = (int*)(ws + 16448);
  int* histE = histU + 2 * HIST_N;
  u8* codes = (u8*)(ws + 32768);
  size_t xcOff = ((size_t)32768 + (size_t)n + 15) & ~(size_t)15;
  float* xc = (float*)(ws + xcOff);
  const bool compact = ws_size >= xcOff + (size_t)n * 4u;

  if (compact) {
    k_minmax<1><<<NBLK, NTHR, 0, stream>>>(in4, n, bmin, bmax, histU, histE, xc);
    k_hist<1><<<NBLK, NTHR, 0, stream>>>(in4, xc, tgt, n, bmin, bmax, histU, histE, codes);
    k_decide_pred<1><<<NBLK, NTHR, 0, stream>>>(in4, codes, n, bmin, bmax, histU, histE, out);
  } else {
    k_minmax<0><<<NBLK, NTHR, 0, stream>>>(in4, n, bmin, bmax, histU, histE, nullptr);
    k_hist<0><<<NBLK, NTHR, 0, stream>>>(in4, nullptr, tgt, n, bmin, bmax, histU, histE, nullptr);
    k_decide_pred<0><<<NBLK, NTHR, 0, stream>>>(in4, nullptr, n, bmin, bmax, histU, histE, out);
  }
}